// Round 18
// baseline (115.619 us; speedup 1.0000x reference)
//
#include <hip/hip_runtime.h>
#include <hip/hip_bf16.h>
#include <cstddef>

namespace {
constexpr int B  = 2;
constexpr int Z  = 200;
constexpr int X  = 200;
constexpr int C  = 128;
constexpr int H  = 4;
constexpr int P  = 8;
constexpr int N  = Z * X;       // 40000
constexpr int BN = B * N;       // 80000
constexpr int SC = 128;         // proj_s cols (f16): [hp][{offx,offy,wp,pad}]
constexpr int NF_P = 14;        // 224/16 output fragments (proj GEMM)
constexpr int NF_O = 8;         // 128/16 output fragments (out GEMM)
constexpr int KS   = 4;         // 128/32 K-steps

typedef __attribute__((ext_vector_type(8))) short short8;
typedef __attribute__((ext_vector_type(4))) float f32x4;
typedef _Float16 h16x2 __attribute__((ext_vector_type(2)));

__device__ inline ushort f2bf(float x) {
    __hip_bfloat16 h = __float2bfloat16(x);
    return *reinterpret_cast<ushort*>(&h);
}
__device__ inline unsigned packbf(float a, float b) {
    return (unsigned)f2bf(a) | ((unsigned)f2bf(b) << 16);
}
__device__ inline ushort f2h(float x) {
    _Float16 h = (_Float16)x;
    return __builtin_bit_cast(ushort, h);
}
__device__ inline float h1f(ushort u) {
    return (float)__builtin_bit_cast(_Float16, u);
}
__device__ inline float2 h2f2(unsigned u) {
    h16x2 h = __builtin_bit_cast(h16x2, u);
    return make_float2((float)h[0], (float)h[1]);
}
__device__ inline unsigned packh(float a, float b) {
    return (unsigned)f2h(a) | ((unsigned)f2h(b) << 16);
}
// packed f32->f16x2 convert (v_cvt_pkrtz_f16_f32), bit-cast to our h16x2
__device__ inline h16x2 pkrtz(float a, float b) {
    return __builtin_bit_cast(h16x2, __builtin_amdgcn_cvt_pkrtz(a, b));
}
// single-instruction lane xor-shuffles (BitMode ds_swizzle), within 32-lane groups
template <int MASK>
__device__ inline float swzx(float x) {
    constexpr int pat = (MASK << 10) | 0x1F;
    return __int_as_float(__builtin_amdgcn_ds_swizzle(__float_as_int(x), pat));
}
template <int MASK>
__device__ inline h16x2 swzh(h16x2 x) {
    constexpr int pat = (MASK << 10) | 0x1F;
    int t = __builtin_amdgcn_ds_swizzle(__builtin_bit_cast(int, x), pat);
    return __builtin_bit_cast(h16x2, t);
}
}

// ---------------------------------------------------------------------------
// W12 = Wout1 @ Wout2 (f32, [129][128]; row 128 = fused bias b12).
// ---------------------------------------------------------------------------
__global__ __launch_bounds__(256) void vsa_k_w12(
    const float* __restrict__ Wout1, const float* __restrict__ bout1,
    const float* __restrict__ Wout2, const float* __restrict__ bout2,
    float* __restrict__ w12)
{
    const int c = threadIdx.x & 127;
    const int k = blockIdx.x * 2 + (threadIdx.x >> 7);
    if (k > 128) return;
    const float* arow = (k < 128) ? (Wout1 + (size_t)k * 128) : bout1;
    float acc = (k < 128) ? 0.f : bout2[c];
    #pragma unroll 4
    for (int j = 0; j < 128; ++j)
        acc = fmaf(arow[j], Wout2[(size_t)j * 128 + c], acc);
    w12[(size_t)k * 128 + c] = acc;
}

// ---------------------------------------------------------------------------
// Prep: pack weights into MFMA fragment order wt[ks][f][lane][8 elems].
// wtp = bf16 (proj GEMM), wtp2 = f16 (out GEMM, from materialized w12).
// ---------------------------------------------------------------------------
__global__ __launch_bounds__(256) void vsa_k_prep(
    const float* __restrict__ Wv,    const float* __restrict__ bv,
    const float* __restrict__ Woff,  const float* __restrict__ boff,
    const float* __restrict__ Wattn, const float* __restrict__ battn,
    const float* __restrict__ w12,
    ushort* __restrict__ wtp, ushort* __restrict__ wtp2,
    float* __restrict__ biasp, float* __restrict__ bias2)
{
    const int u = blockIdx.x * 256 + threadIdx.x;
    constexpr int NP = KS * NF_P * 64;   // 3584
    constexpr int NO = KS * NF_O * 64;   // 2048

    if (u < NP) {
        int ks  = u / (NF_P * 64);
        int rem = u - ks * (NF_P * 64);
        int f = rem >> 6, l = rem & 63;
        int n  = f * 16 + (l & 15);
        int kb = ks * 32 + (l >> 4) * 8;
        float v[8];
        #pragma unroll
        for (int e = 0; e < 8; ++e) {
            int k = kb + e;
            if (n < 128)      v[e] = Wv[k * 128 + n];
            else if (n < 192) v[e] = Woff[k * 64 + (n - 128)];
            else              v[e] = Wattn[k * 32 + (n - 192)];
        }
        unsigned* dst = (unsigned*)(wtp + (size_t)u * 8);
        #pragma unroll
        for (int i = 0; i < 4; ++i) dst[i] = packbf(v[2*i], v[2*i+1]);
    } else if (u < NP + NO) {
        int t   = u - NP;
        int ks  = t / (NF_O * 64);
        int rem = t - ks * (NF_O * 64);
        int f = rem >> 6, l = rem & 63;
        int n  = f * 16 + (l & 15);
        int kb = ks * 32 + (l >> 4) * 8;
        unsigned* dst = (unsigned*)(wtp2 + (size_t)t * 8);
        #pragma unroll
        for (int i = 0; i < 4; ++i)
            dst[i] = packh(w12[(size_t)(kb + 2*i) * 128 + n],
                           w12[(size_t)(kb + 2*i + 1) * 128 + n]);
    } else if (u < NP + NO + 224) {
        int c = u - NP - NO;
        float bb;
        if (c < 128)      bb = bv[c];
        else if (c < 192) bb = boff[c - 128];
        else              bb = battn[c - 192];
        biasp[c] = bb;
    } else if (u < NP + NO + 224 + 128) {
        int c = u - NP - NO - 224;
        bias2[c] = w12[(size_t)128 * 128 + c];
    }
}

// ---------------------------------------------------------------------------
// Fused projection GEMM (MFMA, no LDS) + softmax epilogue.
// TWO A-fragments per wave (32 rows): each B-fragment load feeds 2 MFMAs,
// halving the wtp reload traffic (proj's binder) and the wave count.
//   cols 0..127   -> proj_v16 (f16 values)
//   cols 128..191 -> proj_s16[row][hp*4 + {0,1}] (f16 offsets)
//   cols 192..223 -> softmax per 8-point group -> proj_s16[row][hp*4+2]
// ---------------------------------------------------------------------------
__global__ __launch_bounds__(256) void vsa_k_proj(
    const float* __restrict__ Q, const ushort* __restrict__ wtp,
    const float* __restrict__ biasp,
    ushort* __restrict__ proj_v16, ushort* __restrict__ proj_s16)
{
    const int lane = threadIdx.x & 63;
    const int wave = blockIdx.x * 4 + (threadIdx.x >> 6);
    const int row0 = wave * 32;
    const int m  = lane & 15;
    const int kg = lane >> 4;

    const float* qpA = Q + (size_t)(row0 + m) * 128 + kg * 8;
    const float* qpB = Q + (size_t)(row0 + 16 + m) * 128 + kg * 8;

    f32x4 acc[2][NF_P];
    #pragma unroll
    for (int s = 0; s < 2; ++s)
        #pragma unroll
        for (int f = 0; f < NF_P; ++f) acc[s][f] = (f32x4){0.f, 0.f, 0.f, 0.f};

    #pragma unroll
    for (int ks = 0; ks < KS; ++ks) {
        float4 a0 = *(const float4*)(qpA + ks * 32);
        float4 a1 = *(const float4*)(qpA + ks * 32 + 4);
        float4 b0 = *(const float4*)(qpB + ks * 32);
        float4 b1 = *(const float4*)(qpB + ks * 32 + 4);
        short8 afA, afB;
        afA[0] = (short)f2bf(a0.x); afA[1] = (short)f2bf(a0.y);
        afA[2] = (short)f2bf(a0.z); afA[3] = (short)f2bf(a0.w);
        afA[4] = (short)f2bf(a1.x); afA[5] = (short)f2bf(a1.y);
        afA[6] = (short)f2bf(a1.z); afA[7] = (short)f2bf(a1.w);
        afB[0] = (short)f2bf(b0.x); afB[1] = (short)f2bf(b0.y);
        afB[2] = (short)f2bf(b0.z); afB[3] = (short)f2bf(b0.w);
        afB[4] = (short)f2bf(b1.x); afB[5] = (short)f2bf(b1.y);
        afB[6] = (short)f2bf(b1.z); afB[7] = (short)f2bf(b1.w);
        const short8* wrow = (const short8*)wtp + ks * NF_P * 64 + lane;
        #pragma unroll
        for (int f = 0; f < NF_P; ++f) {
            const short8 wfrag = wrow[f * 64];
            acc[0][f] = __builtin_amdgcn_mfma_f32_16x16x32_bf16(afA, wfrag, acc[0][f], 0, 0, 0);
            acc[1][f] = __builtin_amdgcn_mfma_f32_16x16x32_bf16(afB, wfrag, acc[1][f], 0, 0, 0);
        }
    }

    #pragma unroll
    for (int s = 0; s < 2; ++s) {
        const int rbase = row0 + s * 16;
        // values -> f16
        #pragma unroll
        for (int f = 0; f < 8; ++f) {
            const int col = f * 16 + m;
            const float bb = biasp[col];
            #pragma unroll
            for (int r = 0; r < 4; ++r)
                proj_v16[(size_t)(rbase + kg * 4 + r) * 128 + col] = f2h(acc[s][f][r] + bb);
        }
        // offsets -> f16 at [hp*4 + comp]
        #pragma unroll
        for (int f = 8; f < 12; ++f) {
            const int col = f * 16 + m;
            const float bb = biasp[col];
            const int c  = col - 128;          // 0..63
            const int hp = c >> 1, comp = c & 1;
            #pragma unroll
            for (int r = 0; r < 4; ++r)
                proj_s16[(size_t)(rbase + kg * 4 + r) * SC + hp * 4 + comp] = f2h(acc[s][f][r] + bb);
        }
        // attn logits -> softmax -> f16 weights at [hp*4 + 2]
        #pragma unroll
        for (int f = 12; f < 14; ++f) {
            const float bb = biasp[f * 16 + m];
            const int hp = (f - 12) * 16 + m;  // 0..31
            #pragma unroll
            for (int r = 0; r < 4; ++r) {
                float v = acc[s][f][r] + bb;
                float mx = v;
                mx = fmaxf(mx, swzx<1>(mx));
                mx = fmaxf(mx, swzx<2>(mx));
                mx = fmaxf(mx, swzx<4>(mx));
                float ex = __expf(v - mx);
                float sm = ex;
                sm += swzx<1>(sm); sm += swzx<2>(sm); sm += swzx<4>(sm);
                const float wp = ex / sm;
                proj_s16[(size_t)(rbase + kg * 4 + r) * SC + hp * 4 + 2] = f2h(wp);
            }
        }
    }
}

// ---------------------------------------------------------------------------
// FUSED sampling + output GEMM, 16 waves/block (1024 threads): each wave
// runs only TWO sampling units. One block = 16 consecutive bn rows.
// Sampling results -> LDS (f16, pad-136). Barrier. GEMM: waves 0..7 own one
// output fragment each; waves 8..15 exit. Nontemporal Q/out.
// XCD swizzle: 5000 blocks = 8 x 625.
// ---------------------------------------------------------------------------
__global__ __launch_bounds__(1024) void vsa_k_so(
    const ushort* __restrict__ proj_v16, const ushort* __restrict__ proj_s16,
    const ushort* __restrict__ wtp2, const float* __restrict__ bias2,
    const float* __restrict__ Q, float* __restrict__ out)
{
    __shared__ ushort tmp_lds[16][136];   // 16 rows x 128 f16, pad 8 (16B)

    const int lane = threadIdx.x & 63;
    const int wv   = threadIdx.x >> 6;     // wave 0..15
    const int hsub = lane >> 5;            // head within pair
    const int p    = (lane >> 2) & 7;      // point (bits 2..4)
    const int d8   = lane & 3;             // 8-value quad (bits 0..1)

    const int orig = blockIdx.x;                      // 0..4999
    const int wg   = (orig & 7) * 625 + (orig >> 3);  // bijective (5000%8==0)
    const int b    = wg / 2500;
    const int bl0  = (wg - b * 2500) * 16;            // bn_local0, 0..39984
    const int i0   = bl0 / 200;
    const int j0   = bl0 - i0 * 200;
    const int bn0  = b * N + bl0;

    const ushort* vb = proj_v16 + (size_t)b * N * 128;

    #pragma unroll
    for (int t = 0; t < 2; ++t) {
        const int unit = t * 16 + wv;       // 0..31
        const int pix  = unit >> 1;         // 0..15
        const int h    = (unit & 1) * 2 + hsub;
        const int jr   = j0 + pix;
        const bool wr  = jr >= 200;         // 16 consecutive bn may wrap one i
        const int i    = i0 + (wr ? 1 : 0);
        const int j    = wr ? jr - 200 : jr;
        const int bn   = bn0 + pix;

        // per-point data: one uint2 = {offx, offy, wp, pad} f16
        const uint2 ow = *(const uint2*)(proj_s16 + (size_t)bn * SC + (h * 8 + p) * 4);
        const float2 off = h2f2(ow.x);
        const float  wp  = h1f((ushort)(ow.y & 0xffff));

        const float ixf = (float)i + off.x;
        const float iyf = (float)j + off.y;
        const float x0f = floorf(ixf), y0f = floorf(iyf);
        const float lx = ixf - x0f, ly = iyf - y0f;
        const int x0 = (int)x0f, y0 = (int)y0f;
        const int x1 = x0 + 1,  y1 = y0 + 1;
        const int xc0 = min(max(x0, 0), X - 1), xc1 = min(max(x1, 0), X - 1);
        const int yc0 = min(max(y0, 0), Z - 1), yc1 = min(max(y1, 0), Z - 1);

        const float wx0 = ((unsigned)x0 < (unsigned)X) ? (1.f - lx) : 0.f;
        const float wx1 = ((unsigned)x1 < (unsigned)X) ? lx : 0.f;
        const float wy0 = (((unsigned)y0 < (unsigned)Z) ? (1.f - ly) : 0.f) * wp;
        const float wy1 = (((unsigned)y1 < (unsigned)Z) ? ly : 0.f) * wp;

        const h16x2 w00p = pkrtz(wx0 * wy0, wx0 * wy0);
        const h16x2 w10p = pkrtz(wx1 * wy0, wx1 * wy0);
        const h16x2 w01p = pkrtz(wx0 * wy1, wx0 * wy1);
        const h16x2 w11p = pkrtz(wx1 * wy1, wx1 * wy1);

        const int rb0 = yc0 * X, rb1 = yc1 * X;
        const int hb  = h * 32 + d8 * 8;    // f16-elem offset in 128-elem row

        const uint4 c00 = *(const uint4*)(vb + (size_t)(rb0 + xc0) * 128 + hb);
        const uint4 c10 = *(const uint4*)(vb + (size_t)(rb0 + xc1) * 128 + hb);
        const uint4 c01 = *(const uint4*)(vb + (size_t)(rb1 + xc0) * 128 + hb);
        const uint4 c11 = *(const uint4*)(vb + (size_t)(rb1 + xc1) * 128 + hb);

        h16x2 a0 = (h16x2)0, a1 = (h16x2)0, a2 = (h16x2)0, a3 = (h16x2)0;
        #define VSA_ACC(c, wpk) { \
            a0 = __builtin_elementwise_fma(__builtin_bit_cast(h16x2, (c).x), wpk, a0); \
            a1 = __builtin_elementwise_fma(__builtin_bit_cast(h16x2, (c).y), wpk, a1); \
            a2 = __builtin_elementwise_fma(__builtin_bit_cast(h16x2, (c).z), wpk, a2); \
            a3 = __builtin_elementwise_fma(__builtin_bit_cast(h16x2, (c).w), wpk, a3); }
        VSA_ACC(c00, w00p)
        VSA_ACC(c10, w10p)
        VSA_ACC(c01, w01p)
        VSA_ACC(c11, w11p)
        #undef VSA_ACC

        // reduce over the 8 points (p = lane bits 2..4), within 32 lanes
        a0 += swzh<4>(a0);  a1 += swzh<4>(a1);  a2 += swzh<4>(a2);  a3 += swzh<4>(a3);
        a0 += swzh<8>(a0);  a1 += swzh<8>(a1);  a2 += swzh<8>(a2);  a3 += swzh<8>(a3);
        a0 += swzh<16>(a0); a1 += swzh<16>(a1); a2 += swzh<16>(a2); a3 += swzh<16>(a3);

        if (p == 0) {   // lanes {0..3, 32..35}: one 16B LDS store per head
            uint4 o;
            o.x = __builtin_bit_cast(unsigned, a0);
            o.y = __builtin_bit_cast(unsigned, a1);
            o.z = __builtin_bit_cast(unsigned, a2);
            o.w = __builtin_bit_cast(unsigned, a3);
            *(uint4*)(&tmp_lds[pix][h * 32 + d8 * 8]) = o;
        }
    }

    // ---- prefetch Q residual (GEMM waves only; hides under barrier) ----
    const int m  = lane & 15;
    const int kg = lane >> 4;
    const int col = (wv & 7) * 16 + m;
    float qv[4];
    if (wv < 8) {
        #pragma unroll
        for (int r = 0; r < 4; ++r)
            qv[r] = __builtin_nontemporal_load(Q + (size_t)(bn0 + kg * 4 + r) * 128 + col);
    }

    __syncthreads();
    if (wv >= 8) return;

    // ---- output GEMM phase: wave wv owns fragment wv ----
    f32x4 acc = (f32x4){0.f, 0.f, 0.f, 0.f};
    #pragma unroll
    for (int ks = 0; ks < KS; ++ks) {
        short8 af = *(const short8*)(&tmp_lds[m][ks * 32 + kg * 8]);
        const short8* wrow = (const short8*)wtp2 + ks * NF_O * 64 + lane;
        acc = __builtin_amdgcn_mfma_f32_16x16x32_f16(af, wrow[wv * 64], acc, 0, 0, 0);
    }

    const float bb = bias2[col];
    #pragma unroll
    for (int r = 0; r < 4; ++r) {
        const size_t gi = (size_t)(bn0 + kg * 4 + r) * 128 + col;
        __builtin_nontemporal_store(acc[r] + bb + qv[r], out + gi);
    }
}

// ---------------------------------------------------------------------------
extern "C" void kernel_launch(void* const* d_in, const int* in_sizes, int n_in,
                              void* d_out, int out_size, void* d_ws, size_t ws_size,
                              hipStream_t stream) {
    const float* Q     = (const float*)d_in[0];
    const float* Wv    = (const float*)d_in[1];
    const float* bv    = (const float*)d_in[2];
    const float* Woff  = (const float*)d_in[3];
    const float* boff  = (const float*)d_in[4];
    const float* Wattn = (const float*)d_in[5];
    const float* battn = (const float*)d_in[6];
    const float* Wout1 = (const float*)d_in[7];
    const float* bout1 = (const float*)d_in[8];
    const float* Wout2 = (const float*)d_in[9];
    const float* bout2 = (const float*)d_in[10];
    float* out = (float*)d_out;

    // Workspace: biasp f32[224] | b12 f32[128] | w12 f32[129*128] |
    //            proj_s16 u16[BN][128] | proj_v16 u16[BN][128] | wtp | wtp2
    float*  biasp  = (float*)d_ws;
    float*  bias2  = biasp + 224;
    float*  w12    = bias2 + 128;
    ushort* proj_s16 = (ushort*)(w12 + 129 * 128);
    ushort* proj_v16 = proj_s16 + (size_t)BN * SC;
    ushort* wtp    = proj_v16 + (size_t)BN * 128;
    ushort* wtp2   = wtp + (size_t)KS * NF_P * 64 * 8;

    constexpr int prep_n = KS * NF_P * 64 + KS * NF_O * 64 + 224 + 128; // 5984
    vsa_k_w12<<<65, 256, 0, stream>>>(Wout1, bout1, Wout2, bout2, w12);
    vsa_k_prep<<<(prep_n + 255) / 256, 256, 0, stream>>>(
        Wv, bv, Woff, boff, Wattn, battn, w12, wtp, wtp2, biasp, bias2);
    vsa_k_proj<<<BN / 128, 256, 0, stream>>>(Q, wtp, biasp, proj_v16, proj_s16);
    vsa_k_so<<<BN / 16, 1024, 0, stream>>>(proj_v16, proj_s16, wtp2, bias2, Q, out);
}

// Round 19
// 85.052 us; speedup vs baseline: 1.3594x; 1.3594x over previous
//
#include <hip/hip_runtime.h>
#include <hip/hip_bf16.h>
#include <cstddef>

namespace {
constexpr int B  = 2;
constexpr int Z  = 200;
constexpr int X  = 200;
constexpr int C  = 128;
constexpr int H  = 4;
constexpr int P  = 8;
constexpr int N  = Z * X;       // 40000
constexpr int BN = B * N;       // 80000
constexpr int SC = 128;         // proj_s cols (f16): [hp][{offx,offy,wp,pad}]
constexpr int NF_P = 14;        // 224/16 output fragments (proj GEMM)
constexpr int NF_O = 8;         // 128/16 output fragments (out GEMM)
constexpr int KS   = 4;         // 128/32 K-steps

typedef __attribute__((ext_vector_type(8))) short short8;
typedef __attribute__((ext_vector_type(4))) float f32x4;
typedef _Float16 h16x2 __attribute__((ext_vector_type(2)));

__device__ inline ushort f2bf(float x) {
    __hip_bfloat16 h = __float2bfloat16(x);
    return *reinterpret_cast<ushort*>(&h);
}
__device__ inline unsigned packbf(float a, float b) {
    return (unsigned)f2bf(a) | ((unsigned)f2bf(b) << 16);
}
__device__ inline ushort f2h(float x) {
    _Float16 h = (_Float16)x;
    return __builtin_bit_cast(ushort, h);
}
__device__ inline float h1f(ushort u) {
    return (float)__builtin_bit_cast(_Float16, u);
}
__device__ inline float2 h2f2(unsigned u) {
    h16x2 h = __builtin_bit_cast(h16x2, u);
    return make_float2((float)h[0], (float)h[1]);
}
__device__ inline unsigned packh(float a, float b) {
    return (unsigned)f2h(a) | ((unsigned)f2h(b) << 16);
}
// packed f32->f16x2 convert (v_cvt_pkrtz_f16_f32), bit-cast to our h16x2
__device__ inline h16x2 pkrtz(float a, float b) {
    return __builtin_bit_cast(h16x2, __builtin_amdgcn_cvt_pkrtz(a, b));
}
// single-instruction lane xor-shuffles (BitMode ds_swizzle), within 32-lane groups
template <int MASK>
__device__ inline float swzx(float x) {
    constexpr int pat = (MASK << 10) | 0x1F;
    return __int_as_float(__builtin_amdgcn_ds_swizzle(__float_as_int(x), pat));
}
template <int MASK>
__device__ inline h16x2 swzh(h16x2 x) {
    constexpr int pat = (MASK << 10) | 0x1F;
    int t = __builtin_amdgcn_ds_swizzle(__builtin_bit_cast(int, x), pat);
    return __builtin_bit_cast(h16x2, t);
}
}

// ---------------------------------------------------------------------------
// W12 = Wout1 @ Wout2 (f32, [129][128]; row 128 = fused bias b12).
// ---------------------------------------------------------------------------
__global__ __launch_bounds__(256) void vsa_k_w12(
    const float* __restrict__ Wout1, const float* __restrict__ bout1,
    const float* __restrict__ Wout2, const float* __restrict__ bout2,
    float* __restrict__ w12)
{
    const int c = threadIdx.x & 127;
    const int k = blockIdx.x * 2 + (threadIdx.x >> 7);
    if (k > 128) return;
    const float* arow = (k < 128) ? (Wout1 + (size_t)k * 128) : bout1;
    float acc = (k < 128) ? 0.f : bout2[c];
    #pragma unroll 4
    for (int j = 0; j < 128; ++j)
        acc = fmaf(arow[j], Wout2[(size_t)j * 128 + c], acc);
    w12[(size_t)k * 128 + c] = acc;
}

// ---------------------------------------------------------------------------
// Prep: pack weights into MFMA fragment order wt[ks][f][lane][8 elems].
// wtp = bf16 (proj GEMM), wtp2 = f16 (out GEMM, from materialized w12).
// ---------------------------------------------------------------------------
__global__ __launch_bounds__(256) void vsa_k_prep(
    const float* __restrict__ Wv,    const float* __restrict__ bv,
    const float* __restrict__ Woff,  const float* __restrict__ boff,
    const float* __restrict__ Wattn, const float* __restrict__ battn,
    const float* __restrict__ w12,
    ushort* __restrict__ wtp, ushort* __restrict__ wtp2,
    float* __restrict__ biasp, float* __restrict__ bias2)
{
    const int u = blockIdx.x * 256 + threadIdx.x;
    constexpr int NP = KS * NF_P * 64;   // 3584
    constexpr int NO = KS * NF_O * 64;   // 2048

    if (u < NP) {
        int ks  = u / (NF_P * 64);
        int rem = u - ks * (NF_P * 64);
        int f = rem >> 6, l = rem & 63;
        int n  = f * 16 + (l & 15);
        int kb = ks * 32 + (l >> 4) * 8;
        float v[8];
        #pragma unroll
        for (int e = 0; e < 8; ++e) {
            int k = kb + e;
            if (n < 128)      v[e] = Wv[k * 128 + n];
            else if (n < 192) v[e] = Woff[k * 64 + (n - 128)];
            else              v[e] = Wattn[k * 32 + (n - 192)];
        }
        unsigned* dst = (unsigned*)(wtp + (size_t)u * 8);
        #pragma unroll
        for (int i = 0; i < 4; ++i) dst[i] = packbf(v[2*i], v[2*i+1]);
    } else if (u < NP + NO) {
        int t   = u - NP;
        int ks  = t / (NF_O * 64);
        int rem = t - ks * (NF_O * 64);
        int f = rem >> 6, l = rem & 63;
        int n  = f * 16 + (l & 15);
        int kb = ks * 32 + (l >> 4) * 8;
        unsigned* dst = (unsigned*)(wtp2 + (size_t)t * 8);
        #pragma unroll
        for (int i = 0; i < 4; ++i)
            dst[i] = packh(w12[(size_t)(kb + 2*i) * 128 + n],
                           w12[(size_t)(kb + 2*i + 1) * 128 + n]);
    } else if (u < NP + NO + 224) {
        int c = u - NP - NO;
        float bb;
        if (c < 128)      bb = bv[c];
        else if (c < 192) bb = boff[c - 128];
        else              bb = battn[c - 192];
        biasp[c] = bb;
    } else if (u < NP + NO + 224 + 128) {
        int c = u - NP - NO - 224;
        bias2[c] = w12[(size_t)128 * 128 + c];
    }
}

// ---------------------------------------------------------------------------
// Fused projection GEMM + softmax epilogue, LDS-STAGED B:
// 8-wave (512-thread) blocks stage the whole 57KB wtp table into LDS once
// (7 coalesced 16B loads/thread), then all B-fragments come from
// ds_read_b128 — eliminates the 1.12GB L1/L2 B-reload stream.
// Per-wave structure identical to r17 (1 A-frag, 56 acc VGPRs, no spill).
// ---------------------------------------------------------------------------
__global__ __launch_bounds__(512) void vsa_k_proj(
    const float* __restrict__ Q, const ushort* __restrict__ wtp,
    const float* __restrict__ biasp,
    ushort* __restrict__ proj_v16, ushort* __restrict__ proj_s16)
{
    __shared__ ushort lds_wt[KS * NF_P * 64 * 8];   // 57344 B

    const int tid  = threadIdx.x;
    const int lane = tid & 63;
    const int wv   = tid >> 6;              // 0..7
    const int row0 = blockIdx.x * 128 + wv * 16;
    const int m  = lane & 15;
    const int kg = lane >> 4;

    // stage wtp -> LDS (3584 x 16B, fully coalesced)
    {
        const uint4* src = (const uint4*)wtp;
        uint4* dst = (uint4*)lds_wt;
        #pragma unroll
        for (int it = 0; it < 7; ++it)
            dst[it * 512 + tid] = src[it * 512 + tid];
    }
    __syncthreads();

    const float* qp = Q + (size_t)(row0 + m) * 128 + kg * 8;

    f32x4 acc[NF_P];
    #pragma unroll
    for (int f = 0; f < NF_P; ++f) acc[f] = (f32x4){0.f, 0.f, 0.f, 0.f};

    #pragma unroll
    for (int ks = 0; ks < KS; ++ks) {
        float4 a0 = *(const float4*)(qp + ks * 32);
        float4 a1 = *(const float4*)(qp + ks * 32 + 4);
        short8 af;
        af[0] = (short)f2bf(a0.x); af[1] = (short)f2bf(a0.y);
        af[2] = (short)f2bf(a0.z); af[3] = (short)f2bf(a0.w);
        af[4] = (short)f2bf(a1.x); af[5] = (short)f2bf(a1.y);
        af[6] = (short)f2bf(a1.z); af[7] = (short)f2bf(a1.w);
        const short8* wrow = (const short8*)lds_wt + ks * NF_P * 64 + lane;
        #pragma unroll
        for (int f = 0; f < NF_P; ++f)
            acc[f] = __builtin_amdgcn_mfma_f32_16x16x32_bf16(af, wrow[f * 64], acc[f], 0, 0, 0);
    }

    // values -> f16
    #pragma unroll
    for (int f = 0; f < 8; ++f) {
        const int col = f * 16 + m;
        const float bb = biasp[col];
        #pragma unroll
        for (int r = 0; r < 4; ++r)
            proj_v16[(size_t)(row0 + kg * 4 + r) * 128 + col] = f2h(acc[f][r] + bb);
    }
    // offsets -> f16 at [hp*4 + comp]
    #pragma unroll
    for (int f = 8; f < 12; ++f) {
        const int col = f * 16 + m;
        const float bb = biasp[col];
        const int c  = col - 128;          // 0..63
        const int hp = c >> 1, comp = c & 1;
        #pragma unroll
        for (int r = 0; r < 4; ++r)
            proj_s16[(size_t)(row0 + kg * 4 + r) * SC + hp * 4 + comp] = f2h(acc[f][r] + bb);
    }
    // attn logits -> softmax -> f16 weights at [hp*4 + 2]
    #pragma unroll
    for (int f = 12; f < 14; ++f) {
        const float bb = biasp[f * 16 + m];
        const int hp = (f - 12) * 16 + m;  // 0..31
        #pragma unroll
        for (int r = 0; r < 4; ++r) {
            float v = acc[f][r] + bb;
            float mx = v;
            mx = fmaxf(mx, swzx<1>(mx));
            mx = fmaxf(mx, swzx<2>(mx));
            mx = fmaxf(mx, swzx<4>(mx));
            float ex = __expf(v - mx);
            float sm = ex;
            sm += swzx<1>(sm); sm += swzx<2>(sm); sm += swzx<4>(sm);
            const float wp = ex / sm;
            proj_s16[(size_t)(row0 + kg * 4 + r) * SC + hp * 4 + 2] = f2h(wp);
        }
    }
}

// ---------------------------------------------------------------------------
// FUSED sampling + output GEMM, 16 waves/block (1024 threads): each wave
// runs only TWO sampling units. One block = 16 consecutive bn rows.
// Sampling results -> LDS (f16, pad-136). Barrier. GEMM: waves 0..7 own one
// output fragment each; waves 8..15 exit. Nontemporal Q/out.
// XCD swizzle: 5000 blocks = 8 x 625.
// ---------------------------------------------------------------------------
__global__ __launch_bounds__(1024) void vsa_k_so(
    const ushort* __restrict__ proj_v16, const ushort* __restrict__ proj_s16,
    const ushort* __restrict__ wtp2, const float* __restrict__ bias2,
    const float* __restrict__ Q, float* __restrict__ out)
{
    __shared__ ushort tmp_lds[16][136];   // 16 rows x 128 f16, pad 8 (16B)

    const int lane = threadIdx.x & 63;
    const int wv   = threadIdx.x >> 6;     // wave 0..15
    const int hsub = lane >> 5;            // head within pair
    const int p    = (lane >> 2) & 7;      // point (bits 2..4)
    const int d8   = lane & 3;             // 8-value quad (bits 0..1)

    const int orig = blockIdx.x;                      // 0..4999
    const int wg   = (orig & 7) * 625 + (orig >> 3);  // bijective (5000%8==0)
    const int b    = wg / 2500;
    const int bl0  = (wg - b * 2500) * 16;            // bn_local0, 0..39984
    const int i0   = bl0 / 200;
    const int j0   = bl0 - i0 * 200;
    const int bn0  = b * N + bl0;

    const ushort* vb = proj_v16 + (size_t)b * N * 128;

    #pragma unroll
    for (int t = 0; t < 2; ++t) {
        const int unit = t * 16 + wv;       // 0..31
        const int pix  = unit >> 1;         // 0..15
        const int h    = (unit & 1) * 2 + hsub;
        const int jr   = j0 + pix;
        const bool wr  = jr >= 200;         // 16 consecutive bn may wrap one i
        const int i    = i0 + (wr ? 1 : 0);
        const int j    = wr ? jr - 200 : jr;
        const int bn   = bn0 + pix;

        // per-point data: one uint2 = {offx, offy, wp, pad} f16
        const uint2 ow = *(const uint2*)(proj_s16 + (size_t)bn * SC + (h * 8 + p) * 4);
        const float2 off = h2f2(ow.x);
        const float  wp  = h1f((ushort)(ow.y & 0xffff));

        const float ixf = (float)i + off.x;
        const float iyf = (float)j + off.y;
        const float x0f = floorf(ixf), y0f = floorf(iyf);
        const float lx = ixf - x0f, ly = iyf - y0f;
        const int x0 = (int)x0f, y0 = (int)y0f;
        const int x1 = x0 + 1,  y1 = y0 + 1;
        const int xc0 = min(max(x0, 0), X - 1), xc1 = min(max(x1, 0), X - 1);
        const int yc0 = min(max(y0, 0), Z - 1), yc1 = min(max(y1, 0), Z - 1);

        const float wx0 = ((unsigned)x0 < (unsigned)X) ? (1.f - lx) : 0.f;
        const float wx1 = ((unsigned)x1 < (unsigned)X) ? lx : 0.f;
        const float wy0 = (((unsigned)y0 < (unsigned)Z) ? (1.f - ly) : 0.f) * wp;
        const float wy1 = (((unsigned)y1 < (unsigned)Z) ? ly : 0.f) * wp;

        const h16x2 w00p = pkrtz(wx0 * wy0, wx0 * wy0);
        const h16x2 w10p = pkrtz(wx1 * wy0, wx1 * wy0);
        const h16x2 w01p = pkrtz(wx0 * wy1, wx0 * wy1);
        const h16x2 w11p = pkrtz(wx1 * wy1, wx1 * wy1);

        const int rb0 = yc0 * X, rb1 = yc1 * X;
        const int hb  = h * 32 + d8 * 8;    // f16-elem offset in 128-elem row

        const uint4 c00 = *(const uint4*)(vb + (size_t)(rb0 + xc0) * 128 + hb);
        const uint4 c10 = *(const uint4*)(vb + (size_t)(rb0 + xc1) * 128 + hb);
        const uint4 c01 = *(const uint4*)(vb + (size_t)(rb1 + xc0) * 128 + hb);
        const uint4 c11 = *(const uint4*)(vb + (size_t)(rb1 + xc1) * 128 + hb);

        h16x2 a0 = (h16x2)0, a1 = (h16x2)0, a2 = (h16x2)0, a3 = (h16x2)0;
        #define VSA_ACC(c, wpk) { \
            a0 = __builtin_elementwise_fma(__builtin_bit_cast(h16x2, (c).x), wpk, a0); \
            a1 = __builtin_elementwise_fma(__builtin_bit_cast(h16x2, (c).y), wpk, a1); \
            a2 = __builtin_elementwise_fma(__builtin_bit_cast(h16x2, (c).z), wpk, a2); \
            a3 = __builtin_elementwise_fma(__builtin_bit_cast(h16x2, (c).w), wpk, a3); }
        VSA_ACC(c00, w00p)
        VSA_ACC(c10, w10p)
        VSA_ACC(c01, w01p)
        VSA_ACC(c11, w11p)
        #undef VSA_ACC

        // reduce over the 8 points (p = lane bits 2..4), within 32 lanes
        a0 += swzh<4>(a0);  a1 += swzh<4>(a1);  a2 += swzh<4>(a2);  a3 += swzh<4>(a3);
        a0 += swzh<8>(a0);  a1 += swzh<8>(a1);  a2 += swzh<8>(a2);  a3 += swzh<8>(a3);
        a0 += swzh<16>(a0); a1 += swzh<16>(a1); a2 += swzh<16>(a2); a3 += swzh<16>(a3);

        if (p == 0) {   // lanes {0..3, 32..35}: one 16B LDS store per head
            uint4 o;
            o.x = __builtin_bit_cast(unsigned, a0);
            o.y = __builtin_bit_cast(unsigned, a1);
            o.z = __builtin_bit_cast(unsigned, a2);
            o.w = __builtin_bit_cast(unsigned, a3);
            *(uint4*)(&tmp_lds[pix][h * 32 + d8 * 8]) = o;
        }
    }

    // ---- prefetch Q residual (GEMM waves only; hides under barrier) ----
    const int m  = lane & 15;
    const int kg = lane >> 4;
    const int col = (wv & 7) * 16 + m;
    float qv[4];
    if (wv < 8) {
        #pragma unroll
        for (int r = 0; r < 4; ++r)
            qv[r] = __builtin_nontemporal_load(Q + (size_t)(bn0 + kg * 4 + r) * 128 + col);
    }

    __syncthreads();
    if (wv >= 8) return;

    // ---- output GEMM phase: wave wv owns fragment wv ----
    f32x4 acc = (f32x4){0.f, 0.f, 0.f, 0.f};
    #pragma unroll
    for (int ks = 0; ks < KS; ++ks) {
        short8 af = *(const short8*)(&tmp_lds[m][ks * 32 + kg * 8]);
        const short8* wrow = (const short8*)wtp2 + ks * NF_O * 64 + lane;
        acc = __builtin_amdgcn_mfma_f32_16x16x32_f16(af, wrow[wv * 64], acc, 0, 0, 0);
    }

    const float bb = bias2[col];
    #pragma unroll
    for (int r = 0; r < 4; ++r) {
        const size_t gi = (size_t)(bn0 + kg * 4 + r) * 128 + col;
        __builtin_nontemporal_store(acc[r] + bb + qv[r], out + gi);
    }
}

// ---------------------------------------------------------------------------
extern "C" void kernel_launch(void* const* d_in, const int* in_sizes, int n_in,
                              void* d_out, int out_size, void* d_ws, size_t ws_size,
                              hipStream_t stream) {
    const float* Q     = (const float*)d_in[0];
    const float* Wv    = (const float*)d_in[1];
    const float* bv    = (const float*)d_in[2];
    const float* Woff  = (const float*)d_in[3];
    const float* boff  = (const float*)d_in[4];
    const float* Wattn = (const float*)d_in[5];
    const float* battn = (const float*)d_in[6];
    const float* Wout1 = (const float*)d_in[7];
    const float* bout1 = (const float*)d_in[8];
    const float* Wout2 = (const float*)d_in[9];
    const float* bout2 = (const float*)d_in[10];
    float* out = (float*)d_out;

    // Workspace: biasp f32[224] | b12 f32[128] | w12 f32[129*128] |
    //            proj_s16 u16[BN][128] | proj_v16 u16[BN][128] | wtp | wtp2
    float*  biasp  = (float*)d_ws;
    float*  bias2  = biasp + 224;
    float*  w12    = bias2 + 128;
    ushort* proj_s16 = (ushort*)(w12 + 129 * 128);
    ushort* proj_v16 = proj_s16 + (size_t)BN * SC;
    ushort* wtp    = proj_v16 + (size_t)BN * 128;
    ushort* wtp2   = wtp + (size_t)KS * NF_P * 64 * 8;

    constexpr int prep_n = KS * NF_P * 64 + KS * NF_O * 64 + 224 + 128; // 5984
    vsa_k_w12<<<65, 256, 0, stream>>>(Wout1, bout1, Wout2, bout2, w12);
    vsa_k_prep<<<(prep_n + 255) / 256, 256, 0, stream>>>(
        Wv, bv, Woff, boff, Wattn, battn, w12, wtp, wtp2, biasp, bias2);
    vsa_k_proj<<<BN / 128, 512, 0, stream>>>(Q, wtp, biasp, proj_v16, proj_s16);
    vsa_k_so<<<BN / 16, 1024, 0, stream>>>(proj_v16, proj_s16, wtp2, bias2, Q, out);
}

// Round 20
// 84.932 us; speedup vs baseline: 1.3613x; 1.0014x over previous
//
#include <hip/hip_runtime.h>
#include <hip/hip_bf16.h>
#include <cstddef>

namespace {
constexpr int B  = 2;
constexpr int Z  = 200;
constexpr int X  = 200;
constexpr int C  = 128;
constexpr int H  = 4;
constexpr int P  = 8;
constexpr int N  = Z * X;       // 40000
constexpr int BN = B * N;       // 80000
constexpr int SC = 128;         // proj_s cols (f16): [hp][{offx,offy,wp,pad}]
constexpr int NF_P = 14;        // 224/16 output fragments (proj GEMM)
constexpr int NF_O = 8;         // 128/16 output fragments (out GEMM)
constexpr int KS   = 4;         // 128/32 K-steps

typedef __attribute__((ext_vector_type(8))) short short8;
typedef __attribute__((ext_vector_type(4))) float f32x4;
typedef _Float16 h16x2 __attribute__((ext_vector_type(2)));

__device__ inline ushort f2bf(float x) {
    __hip_bfloat16 h = __float2bfloat16(x);
    return *reinterpret_cast<ushort*>(&h);
}
__device__ inline unsigned packbf(float a, float b) {
    return (unsigned)f2bf(a) | ((unsigned)f2bf(b) << 16);
}
__device__ inline ushort f2h(float x) {
    _Float16 h = (_Float16)x;
    return __builtin_bit_cast(ushort, h);
}
__device__ inline float h1f(ushort u) {
    return (float)__builtin_bit_cast(_Float16, u);
}
__device__ inline float2 h2f2(unsigned u) {
    h16x2 h = __builtin_bit_cast(h16x2, u);
    return make_float2((float)h[0], (float)h[1]);
}
__device__ inline unsigned packh(float a, float b) {
    return (unsigned)f2h(a) | ((unsigned)f2h(b) << 16);
}
// packed f32->f16x2 convert (v_cvt_pkrtz_f16_f32), bit-cast to our h16x2
__device__ inline h16x2 pkrtz(float a, float b) {
    return __builtin_bit_cast(h16x2, __builtin_amdgcn_cvt_pkrtz(a, b));
}
// single-instruction lane xor-shuffles (BitMode ds_swizzle), within 32-lane groups
template <int MASK>
__device__ inline float swzx(float x) {
    constexpr int pat = (MASK << 10) | 0x1F;
    return __int_as_float(__builtin_amdgcn_ds_swizzle(__float_as_int(x), pat));
}
template <int MASK>
__device__ inline h16x2 swzh(h16x2 x) {
    constexpr int pat = (MASK << 10) | 0x1F;
    int t = __builtin_amdgcn_ds_swizzle(__builtin_bit_cast(int, x), pat);
    return __builtin_bit_cast(h16x2, t);
}
}

// ---------------------------------------------------------------------------
// W12 = Wout1 @ Wout2 (f32, [129][128]; row 128 = fused bias b12).
// ---------------------------------------------------------------------------
__global__ __launch_bounds__(256) void vsa_k_w12(
    const float* __restrict__ Wout1, const float* __restrict__ bout1,
    const float* __restrict__ Wout2, const float* __restrict__ bout2,
    float* __restrict__ w12)
{
    const int c = threadIdx.x & 127;
    const int k = blockIdx.x * 2 + (threadIdx.x >> 7);
    if (k > 128) return;
    const float* arow = (k < 128) ? (Wout1 + (size_t)k * 128) : bout1;
    float acc = (k < 128) ? 0.f : bout2[c];
    #pragma unroll 4
    for (int j = 0; j < 128; ++j)
        acc = fmaf(arow[j], Wout2[(size_t)j * 128 + c], acc);
    w12[(size_t)k * 128 + c] = acc;
}

// ---------------------------------------------------------------------------
// Prep: pack weights into MFMA fragment order wt[ks][f][lane][8 elems].
// wtp = bf16 (proj GEMM), wtp2 = f16 (out GEMM, from materialized w12).
// ---------------------------------------------------------------------------
__global__ __launch_bounds__(256) void vsa_k_prep(
    const float* __restrict__ Wv,    const float* __restrict__ bv,
    const float* __restrict__ Woff,  const float* __restrict__ boff,
    const float* __restrict__ Wattn, const float* __restrict__ battn,
    const float* __restrict__ w12,
    ushort* __restrict__ wtp, ushort* __restrict__ wtp2,
    float* __restrict__ biasp, float* __restrict__ bias2)
{
    const int u = blockIdx.x * 256 + threadIdx.x;
    constexpr int NP = KS * NF_P * 64;   // 3584
    constexpr int NO = KS * NF_O * 64;   // 2048

    if (u < NP) {
        int ks  = u / (NF_P * 64);
        int rem = u - ks * (NF_P * 64);
        int f = rem >> 6, l = rem & 63;
        int n  = f * 16 + (l & 15);
        int kb = ks * 32 + (l >> 4) * 8;
        float v[8];
        #pragma unroll
        for (int e = 0; e < 8; ++e) {
            int k = kb + e;
            if (n < 128)      v[e] = Wv[k * 128 + n];
            else if (n < 192) v[e] = Woff[k * 64 + (n - 128)];
            else              v[e] = Wattn[k * 32 + (n - 192)];
        }
        unsigned* dst = (unsigned*)(wtp + (size_t)u * 8);
        #pragma unroll
        for (int i = 0; i < 4; ++i) dst[i] = packbf(v[2*i], v[2*i+1]);
    } else if (u < NP + NO) {
        int t   = u - NP;
        int ks  = t / (NF_O * 64);
        int rem = t - ks * (NF_O * 64);
        int f = rem >> 6, l = rem & 63;
        int n  = f * 16 + (l & 15);
        int kb = ks * 32 + (l >> 4) * 8;
        unsigned* dst = (unsigned*)(wtp2 + (size_t)t * 8);
        #pragma unroll
        for (int i = 0; i < 4; ++i)
            dst[i] = packh(w12[(size_t)(kb + 2*i) * 128 + n],
                           w12[(size_t)(kb + 2*i + 1) * 128 + n]);
    } else if (u < NP + NO + 224) {
        int c = u - NP - NO;
        float bb;
        if (c < 128)      bb = bv[c];
        else if (c < 192) bb = boff[c - 128];
        else              bb = battn[c - 192];
        biasp[c] = bb;
    } else if (u < NP + NO + 224 + 128) {
        int c = u - NP - NO - 224;
        bias2[c] = w12[(size_t)128 * 128 + c];
    }
}

// ---------------------------------------------------------------------------
// Fused projection GEMM + softmax epilogue, LDS-STAGED B:
// 8-wave (512-thread) blocks stage the whole 57KB wtp table into LDS once
// (7 coalesced 16B loads/thread), then all B-fragments come from
// ds_read_b128 — eliminates the 1.12GB L1/L2 B-reload stream.
// Per-wave structure identical to r17 (1 A-frag, 56 acc VGPRs, no spill).
// ---------------------------------------------------------------------------
__global__ __launch_bounds__(512) void vsa_k_proj(
    const float* __restrict__ Q, const ushort* __restrict__ wtp,
    const float* __restrict__ biasp,
    ushort* __restrict__ proj_v16, ushort* __restrict__ proj_s16)
{
    __shared__ ushort lds_wt[KS * NF_P * 64 * 8];   // 57344 B

    const int tid  = threadIdx.x;
    const int lane = tid & 63;
    const int wv   = tid >> 6;              // 0..7
    const int row0 = blockIdx.x * 128 + wv * 16;
    const int m  = lane & 15;
    const int kg = lane >> 4;

    // stage wtp -> LDS (3584 x 16B, fully coalesced)
    {
        const uint4* src = (const uint4*)wtp;
        uint4* dst = (uint4*)lds_wt;
        #pragma unroll
        for (int it = 0; it < 7; ++it)
            dst[it * 512 + tid] = src[it * 512 + tid];
    }
    __syncthreads();

    const float* qp = Q + (size_t)(row0 + m) * 128 + kg * 8;

    f32x4 acc[NF_P];
    #pragma unroll
    for (int f = 0; f < NF_P; ++f) acc[f] = (f32x4){0.f, 0.f, 0.f, 0.f};

    #pragma unroll
    for (int ks = 0; ks < KS; ++ks) {
        float4 a0 = *(const float4*)(qp + ks * 32);
        float4 a1 = *(const float4*)(qp + ks * 32 + 4);
        short8 af;
        af[0] = (short)f2bf(a0.x); af[1] = (short)f2bf(a0.y);
        af[2] = (short)f2bf(a0.z); af[3] = (short)f2bf(a0.w);
        af[4] = (short)f2bf(a1.x); af[5] = (short)f2bf(a1.y);
        af[6] = (short)f2bf(a1.z); af[7] = (short)f2bf(a1.w);
        const short8* wrow = (const short8*)lds_wt + ks * NF_P * 64 + lane;
        #pragma unroll
        for (int f = 0; f < NF_P; ++f)
            acc[f] = __builtin_amdgcn_mfma_f32_16x16x32_bf16(af, wrow[f * 64], acc[f], 0, 0, 0);
    }

    // values -> f16
    #pragma unroll
    for (int f = 0; f < 8; ++f) {
        const int col = f * 16 + m;
        const float bb = biasp[col];
        #pragma unroll
        for (int r = 0; r < 4; ++r)
            proj_v16[(size_t)(row0 + kg * 4 + r) * 128 + col] = f2h(acc[f][r] + bb);
    }
    // offsets -> f16 at [hp*4 + comp]
    #pragma unroll
    for (int f = 8; f < 12; ++f) {
        const int col = f * 16 + m;
        const float bb = biasp[col];
        const int c  = col - 128;          // 0..63
        const int hp = c >> 1, comp = c & 1;
        #pragma unroll
        for (int r = 0; r < 4; ++r)
            proj_s16[(size_t)(row0 + kg * 4 + r) * SC + hp * 4 + comp] = f2h(acc[f][r] + bb);
    }
    // attn logits -> softmax -> f16 weights at [hp*4 + 2]
    #pragma unroll
    for (int f = 12; f < 14; ++f) {
        const float bb = biasp[f * 16 + m];
        const int hp = (f - 12) * 16 + m;  // 0..31
        #pragma unroll
        for (int r = 0; r < 4; ++r) {
            float v = acc[f][r] + bb;
            float mx = v;
            mx = fmaxf(mx, swzx<1>(mx));
            mx = fmaxf(mx, swzx<2>(mx));
            mx = fmaxf(mx, swzx<4>(mx));
            float ex = __expf(v - mx);
            float sm = ex;
            sm += swzx<1>(sm); sm += swzx<2>(sm); sm += swzx<4>(sm);
            const float wp = ex / sm;
            proj_s16[(size_t)(row0 + kg * 4 + r) * SC + hp * 4 + 2] = f2h(wp);
        }
    }
}

// ---------------------------------------------------------------------------
// FUSED sampling + output GEMM, 16 waves/block (1024 threads): each wave
// runs only TWO sampling units. One block = 16 consecutive bn rows.
// Sampling results -> LDS (f16, pad-136). Barrier. GEMM: waves 0..7 own one
// output fragment each; waves 8..15 exit. Nontemporal Q/out.
// XCD swizzle: 5000 blocks = 8 x 625.
// ---------------------------------------------------------------------------
__global__ __launch_bounds__(1024) void vsa_k_so(
    const ushort* __restrict__ proj_v16, const ushort* __restrict__ proj_s16,
    const ushort* __restrict__ wtp2, const float* __restrict__ bias2,
    const float* __restrict__ Q, float* __restrict__ out)
{
    __shared__ ushort tmp_lds[16][136];   // 16 rows x 128 f16, pad 8 (16B)

    const int lane = threadIdx.x & 63;
    const int wv   = threadIdx.x >> 6;     // wave 0..15
    const int hsub = lane >> 5;            // head within pair
    const int p    = (lane >> 2) & 7;      // point (bits 2..4)
    const int d8   = lane & 3;             // 8-value quad (bits 0..1)

    const int orig = blockIdx.x;                      // 0..4999
    const int wg   = (orig & 7) * 625 + (orig >> 3);  // bijective (5000%8==0)
    const int b    = wg / 2500;
    const int bl0  = (wg - b * 2500) * 16;            // bn_local0, 0..39984
    const int i0   = bl0 / 200;
    const int j0   = bl0 - i0 * 200;
    const int bn0  = b * N + bl0;

    const ushort* vb = proj_v16 + (size_t)b * N * 128;

    #pragma unroll
    for (int t = 0; t < 2; ++t) {
        const int unit = t * 16 + wv;       // 0..31
        const int pix  = unit >> 1;         // 0..15
        const int h    = (unit & 1) * 2 + hsub;
        const int jr   = j0 + pix;
        const bool wr  = jr >= 200;         // 16 consecutive bn may wrap one i
        const int i    = i0 + (wr ? 1 : 0);
        const int j    = wr ? jr - 200 : jr;
        const int bn   = bn0 + pix;

        // per-point data: one uint2 = {offx, offy, wp, pad} f16
        const uint2 ow = *(const uint2*)(proj_s16 + (size_t)bn * SC + (h * 8 + p) * 4);
        const float2 off = h2f2(ow.x);
        const float  wp  = h1f((ushort)(ow.y & 0xffff));

        const float ixf = (float)i + off.x;
        const float iyf = (float)j + off.y;
        const float x0f = floorf(ixf), y0f = floorf(iyf);
        const float lx = ixf - x0f, ly = iyf - y0f;
        const int x0 = (int)x0f, y0 = (int)y0f;
        const int x1 = x0 + 1,  y1 = y0 + 1;
        const int xc0 = min(max(x0, 0), X - 1), xc1 = min(max(x1, 0), X - 1);
        const int yc0 = min(max(y0, 0), Z - 1), yc1 = min(max(y1, 0), Z - 1);

        const float wx0 = ((unsigned)x0 < (unsigned)X) ? (1.f - lx) : 0.f;
        const float wx1 = ((unsigned)x1 < (unsigned)X) ? lx : 0.f;
        const float wy0 = (((unsigned)y0 < (unsigned)Z) ? (1.f - ly) : 0.f) * wp;
        const float wy1 = (((unsigned)y1 < (unsigned)Z) ? ly : 0.f) * wp;

        const h16x2 w00p = pkrtz(wx0 * wy0, wx0 * wy0);
        const h16x2 w10p = pkrtz(wx1 * wy0, wx1 * wy0);
        const h16x2 w01p = pkrtz(wx0 * wy1, wx0 * wy1);
        const h16x2 w11p = pkrtz(wx1 * wy1, wx1 * wy1);

        const int rb0 = yc0 * X, rb1 = yc1 * X;
        const int hb  = h * 32 + d8 * 8;    // f16-elem offset in 128-elem row

        const uint4 c00 = *(const uint4*)(vb + (size_t)(rb0 + xc0) * 128 + hb);
        const uint4 c10 = *(const uint4*)(vb + (size_t)(rb0 + xc1) * 128 + hb);
        const uint4 c01 = *(const uint4*)(vb + (size_t)(rb1 + xc0) * 128 + hb);
        const uint4 c11 = *(const uint4*)(vb + (size_t)(rb1 + xc1) * 128 + hb);

        h16x2 a0 = (h16x2)0, a1 = (h16x2)0, a2 = (h16x2)0, a3 = (h16x2)0;
        #define VSA_ACC(c, wpk) { \
            a0 = __builtin_elementwise_fma(__builtin_bit_cast(h16x2, (c).x), wpk, a0); \
            a1 = __builtin_elementwise_fma(__builtin_bit_cast(h16x2, (c).y), wpk, a1); \
            a2 = __builtin_elementwise_fma(__builtin_bit_cast(h16x2, (c).z), wpk, a2); \
            a3 = __builtin_elementwise_fma(__builtin_bit_cast(h16x2, (c).w), wpk, a3); }
        VSA_ACC(c00, w00p)
        VSA_ACC(c10, w10p)
        VSA_ACC(c01, w01p)
        VSA_ACC(c11, w11p)
        #undef VSA_ACC

        // reduce over the 8 points (p = lane bits 2..4), within 32 lanes
        a0 += swzh<4>(a0);  a1 += swzh<4>(a1);  a2 += swzh<4>(a2);  a3 += swzh<4>(a3);
        a0 += swzh<8>(a0);  a1 += swzh<8>(a1);  a2 += swzh<8>(a2);  a3 += swzh<8>(a3);
        a0 += swzh<16>(a0); a1 += swzh<16>(a1); a2 += swzh<16>(a2); a3 += swzh<16>(a3);

        if (p == 0) {   // lanes {0..3, 32..35}: one 16B LDS store per head
            uint4 o;
            o.x = __builtin_bit_cast(unsigned, a0);
            o.y = __builtin_bit_cast(unsigned, a1);
            o.z = __builtin_bit_cast(unsigned, a2);
            o.w = __builtin_bit_cast(unsigned, a3);
            *(uint4*)(&tmp_lds[pix][h * 32 + d8 * 8]) = o;
        }
    }

    // ---- prefetch Q residual (GEMM waves only; hides under barrier) ----
    const int m  = lane & 15;
    const int kg = lane >> 4;
    const int col = (wv & 7) * 16 + m;
    float qv[4];
    if (wv < 8) {
        #pragma unroll
        for (int r = 0; r < 4; ++r)
            qv[r] = __builtin_nontemporal_load(Q + (size_t)(bn0 + kg * 4 + r) * 128 + col);
    }

    __syncthreads();
    if (wv >= 8) return;

    // ---- output GEMM phase: wave wv owns fragment wv ----
    f32x4 acc = (f32x4){0.f, 0.f, 0.f, 0.f};
    #pragma unroll
    for (int ks = 0; ks < KS; ++ks) {
        short8 af = *(const short8*)(&tmp_lds[m][ks * 32 + kg * 8]);
        const short8* wrow = (const short8*)wtp2 + ks * NF_O * 64 + lane;
        acc = __builtin_amdgcn_mfma_f32_16x16x32_f16(af, wrow[wv * 64], acc, 0, 0, 0);
    }

    const float bb = bias2[col];
    #pragma unroll
    for (int r = 0; r < 4; ++r) {
        const size_t gi = (size_t)(bn0 + kg * 4 + r) * 128 + col;
        __builtin_nontemporal_store(acc[r] + bb + qv[r], out + gi);
    }
}

// ---------------------------------------------------------------------------
extern "C" void kernel_launch(void* const* d_in, const int* in_sizes, int n_in,
                              void* d_out, int out_size, void* d_ws, size_t ws_size,
                              hipStream_t stream) {
    const float* Q     = (const float*)d_in[0];
    const float* Wv    = (const float*)d_in[1];
    const float* bv    = (const float*)d_in[2];
    const float* Woff  = (const float*)d_in[3];
    const float* boff  = (const float*)d_in[4];
    const float* Wattn = (const float*)d_in[5];
    const float* battn = (const float*)d_in[6];
    const float* Wout1 = (const float*)d_in[7];
    const float* bout1 = (const float*)d_in[8];
    const float* Wout2 = (const float*)d_in[9];
    const float* bout2 = (const float*)d_in[10];
    float* out = (float*)d_out;

    // Workspace: biasp f32[224] | b12 f32[128] | w12 f32[129*128] |
    //            proj_s16 u16[BN][128] | proj_v16 u16[BN][128] | wtp | wtp2
    float*  biasp  = (float*)d_ws;
    float*  bias2  = biasp + 224;
    float*  w12    = bias2 + 128;
    ushort* proj_s16 = (ushort*)(w12 + 129 * 128);
    ushort* proj_v16 = proj_s16 + (size_t)BN * SC;
    ushort* wtp    = proj_v16 + (size_t)BN * 128;
    ushort* wtp2   = wtp + (size_t)KS * NF_P * 64 * 8;

    constexpr int prep_n = KS * NF_P * 64 + KS * NF_O * 64 + 224 + 128; // 5984
    vsa_k_w12<<<65, 256, 0, stream>>>(Wout1, bout1, Wout2, bout2, w12);
    vsa_k_prep<<<(prep_n + 255) / 256, 256, 0, stream>>>(
        Wv, bv, Woff, boff, Wattn, battn, w12, wtp, wtp2, biasp, bias2);
    vsa_k_proj<<<BN / 128, 512, 0, stream>>>(Q, wtp, biasp, proj_v16, proj_s16);
    vsa_k_so<<<BN / 16, 1024, 0, stream>>>(proj_v16, proj_s16, wtp2, bias2, Q, out);
}

// Round 21
// 83.478 us; speedup vs baseline: 1.3850x; 1.0174x over previous
//
#include <hip/hip_runtime.h>
#include <hip/hip_bf16.h>
#include <cstddef>

namespace {
constexpr int B  = 2;
constexpr int Z  = 200;
constexpr int X  = 200;
constexpr int C  = 128;
constexpr int H  = 4;
constexpr int P  = 8;
constexpr int N  = Z * X;       // 40000
constexpr int BN = B * N;       // 80000
constexpr int SC = 128;         // proj_s cols (f16): [hp][{offx,offy,wp,pad}]
constexpr int NF_P = 14;        // 224/16 output fragments (proj GEMM)
constexpr int NF_O = 8;         // 128/16 output fragments (out GEMM)
constexpr int KS   = 4;         // 128/32 K-steps

typedef __attribute__((ext_vector_type(8))) short short8;
typedef __attribute__((ext_vector_type(4))) float f32x4;
typedef _Float16 h16x2 __attribute__((ext_vector_type(2)));

__device__ inline ushort f2bf(float x) {
    __hip_bfloat16 h = __float2bfloat16(x);
    return *reinterpret_cast<ushort*>(&h);
}
__device__ inline unsigned packbf(float a, float b) {
    return (unsigned)f2bf(a) | ((unsigned)f2bf(b) << 16);
}
__device__ inline ushort f2h(float x) {
    _Float16 h = (_Float16)x;
    return __builtin_bit_cast(ushort, h);
}
__device__ inline float h1f(ushort u) {
    return (float)__builtin_bit_cast(_Float16, u);
}
__device__ inline float2 h2f2(unsigned u) {
    h16x2 h = __builtin_bit_cast(h16x2, u);
    return make_float2((float)h[0], (float)h[1]);
}
__device__ inline unsigned packh(float a, float b) {
    return (unsigned)f2h(a) | ((unsigned)f2h(b) << 16);
}
// packed f32->f16x2 convert (v_cvt_pkrtz_f16_f32), bit-cast to our h16x2
__device__ inline h16x2 pkrtz(float a, float b) {
    return __builtin_bit_cast(h16x2, __builtin_amdgcn_cvt_pkrtz(a, b));
}
// single-instruction lane xor-shuffles (BitMode ds_swizzle), within 32-lane groups
template <int MASK>
__device__ inline float swzx(float x) {
    constexpr int pat = (MASK << 10) | 0x1F;
    return __int_as_float(__builtin_amdgcn_ds_swizzle(__float_as_int(x), pat));
}
template <int MASK>
__device__ inline h16x2 swzh(h16x2 x) {
    constexpr int pat = (MASK << 10) | 0x1F;
    int t = __builtin_amdgcn_ds_swizzle(__builtin_bit_cast(int, x), pat);
    return __builtin_bit_cast(h16x2, t);
}
}

// ---------------------------------------------------------------------------
// SETUP (merged w12 + prep, no intermediate w12 buffer, no serial dependency):
//   blocks 0..64   : thread (k = blk*2 + tid>>7, c = tid&127) computes
//                    W12[k][c] = Wout1[k]·Wout2[:,c] (row 128 = bias) and
//                    scatter-writes it DIRECTLY into the packed f16 wtp2
//                    fragment table (or bias2 for k==128).
//   blocks 65..79  : wtp (bf16 proj-GEMM fragments) + biasp[224].
// ---------------------------------------------------------------------------
__global__ __launch_bounds__(256) void vsa_k_setup(
    const float* __restrict__ Wv,    const float* __restrict__ bv,
    const float* __restrict__ Woff,  const float* __restrict__ boff,
    const float* __restrict__ Wattn, const float* __restrict__ battn,
    const float* __restrict__ Wout1, const float* __restrict__ bout1,
    const float* __restrict__ Wout2, const float* __restrict__ bout2,
    ushort* __restrict__ wtp, ushort* __restrict__ wtp2,
    float* __restrict__ biasp, float* __restrict__ bias2)
{
    constexpr int NP = KS * NF_P * 64;   // 3584

    if (blockIdx.x < 65) {
        const int c = threadIdx.x & 127;
        const int k = blockIdx.x * 2 + (threadIdx.x >> 7);
        if (k > 128) return;
        const float* arow = (k < 128) ? (Wout1 + (size_t)k * 128) : bout1;
        float acc = (k < 128) ? 0.f : bout2[c];
        #pragma unroll 4
        for (int j = 0; j < 128; ++j)
            acc = fmaf(arow[j], Wout2[(size_t)j * 128 + c], acc);
        if (k < 128) {
            // scatter into wtp2[t*8 + e]: t = ks*(8*64) + f*64 + l
            const int ks = k >> 5;
            const int l  = (((k >> 3) & 3) << 4) | (c & 15);
            const int f  = c >> 4;
            const int t  = (ks * NF_O + f) * 64 + l;
            wtp2[(size_t)t * 8 + (k & 7)] = f2h(acc);
        } else {
            bias2[c] = acc;
        }
        return;
    }

    const int u = (blockIdx.x - 65) * 256 + threadIdx.x;
    if (u < NP) {
        int ks  = u / (NF_P * 64);
        int rem = u - ks * (NF_P * 64);
        int f = rem >> 6, l = rem & 63;
        int n  = f * 16 + (l & 15);
        int kb = ks * 32 + (l >> 4) * 8;
        float v[8];
        #pragma unroll
        for (int e = 0; e < 8; ++e) {
            int k = kb + e;
            if (n < 128)      v[e] = Wv[k * 128 + n];
            else if (n < 192) v[e] = Woff[k * 64 + (n - 128)];
            else              v[e] = Wattn[k * 32 + (n - 192)];
        }
        unsigned* dst = (unsigned*)(wtp + (size_t)u * 8);
        #pragma unroll
        for (int i = 0; i < 4; ++i) dst[i] = packbf(v[2*i], v[2*i+1]);
    } else if (u < NP + 224) {
        int c = u - NP;
        float bb;
        if (c < 128)      bb = bv[c];
        else if (c < 192) bb = boff[c - 128];
        else              bb = battn[c - 192];
        biasp[c] = bb;
    }
}

// ---------------------------------------------------------------------------
// Fused projection GEMM + softmax epilogue, LDS-STAGED B (r19 structure):
// 8-wave blocks stage the 57KB wtp table into LDS once; B-fragments come
// from ds_read_b128 — no L1/L2 B-reload stream.
// ---------------------------------------------------------------------------
__global__ __launch_bounds__(512) void vsa_k_proj(
    const float* __restrict__ Q, const ushort* __restrict__ wtp,
    const float* __restrict__ biasp,
    ushort* __restrict__ proj_v16, ushort* __restrict__ proj_s16)
{
    __shared__ ushort lds_wt[KS * NF_P * 64 * 8];   // 57344 B

    const int tid  = threadIdx.x;
    const int lane = tid & 63;
    const int wv   = tid >> 6;              // 0..7
    const int row0 = blockIdx.x * 128 + wv * 16;
    const int m  = lane & 15;
    const int kg = lane >> 4;

    // stage wtp -> LDS (3584 x 16B, fully coalesced)
    {
        const uint4* src = (const uint4*)wtp;
        uint4* dst = (uint4*)lds_wt;
        #pragma unroll
        for (int it = 0; it < 7; ++it)
            dst[it * 512 + tid] = src[it * 512 + tid];
    }
    __syncthreads();

    const float* qp = Q + (size_t)(row0 + m) * 128 + kg * 8;

    f32x4 acc[NF_P];
    #pragma unroll
    for (int f = 0; f < NF_P; ++f) acc[f] = (f32x4){0.f, 0.f, 0.f, 0.f};

    #pragma unroll
    for (int ks = 0; ks < KS; ++ks) {
        float4 a0 = *(const float4*)(qp + ks * 32);
        float4 a1 = *(const float4*)(qp + ks * 32 + 4);
        short8 af;
        af[0] = (short)f2bf(a0.x); af[1] = (short)f2bf(a0.y);
        af[2] = (short)f2bf(a0.z); af[3] = (short)f2bf(a0.w);
        af[4] = (short)f2bf(a1.x); af[5] = (short)f2bf(a1.y);
        af[6] = (short)f2bf(a1.z); af[7] = (short)f2bf(a1.w);
        const short8* wrow = (const short8*)lds_wt + ks * NF_P * 64 + lane;
        #pragma unroll
        for (int f = 0; f < NF_P; ++f)
            acc[f] = __builtin_amdgcn_mfma_f32_16x16x32_bf16(af, wrow[f * 64], acc[f], 0, 0, 0);
    }

    // values -> f16
    #pragma unroll
    for (int f = 0; f < 8; ++f) {
        const int col = f * 16 + m;
        const float bb = biasp[col];
        #pragma unroll
        for (int r = 0; r < 4; ++r)
            proj_v16[(size_t)(row0 + kg * 4 + r) * 128 + col] = f2h(acc[f][r] + bb);
    }
    // offsets -> f16 at [hp*4 + comp]
    #pragma unroll
    for (int f = 8; f < 12; ++f) {
        const int col = f * 16 + m;
        const float bb = biasp[col];
        const int c  = col - 128;          // 0..63
        const int hp = c >> 1, comp = c & 1;
        #pragma unroll
        for (int r = 0; r < 4; ++r)
            proj_s16[(size_t)(row0 + kg * 4 + r) * SC + hp * 4 + comp] = f2h(acc[f][r] + bb);
    }
    // attn logits -> softmax -> f16 weights at [hp*4 + 2]
    #pragma unroll
    for (int f = 12; f < 14; ++f) {
        const float bb = biasp[f * 16 + m];
        const int hp = (f - 12) * 16 + m;  // 0..31
        #pragma unroll
        for (int r = 0; r < 4; ++r) {
            float v = acc[f][r] + bb;
            float mx = v;
            mx = fmaxf(mx, swzx<1>(mx));
            mx = fmaxf(mx, swzx<2>(mx));
            mx = fmaxf(mx, swzx<4>(mx));
            float ex = __expf(v - mx);
            float sm = ex;
            sm += swzx<1>(sm); sm += swzx<2>(sm); sm += swzx<4>(sm);
            const float wp = ex / sm;
            proj_s16[(size_t)(row0 + kg * 4 + r) * SC + hp * 4 + 2] = f2h(wp);
        }
    }
}

// ---------------------------------------------------------------------------
// FUSED sampling + output GEMM, 16 waves/block; each wave runs two sampling
// units. ow records for BOTH units and the GEMM waves' B-fragments + Q
// residual are loaded UPFRONT (latency hidden under sampling math).
// Barrier. GEMM: waves 0..7 own one output fragment; waves 8..15 exit.
// XCD swizzle: 5000 blocks = 8 x 625.
// ---------------------------------------------------------------------------
__global__ __launch_bounds__(1024) void vsa_k_so(
    const ushort* __restrict__ proj_v16, const ushort* __restrict__ proj_s16,
    const ushort* __restrict__ wtp2, const float* __restrict__ bias2,
    const float* __restrict__ Q, float* __restrict__ out)
{
    __shared__ ushort tmp_lds[16][136];   // 16 rows x 128 f16, pad 8 (16B)

    const int lane = threadIdx.x & 63;
    const int wv   = threadIdx.x >> 6;     // wave 0..15
    const int hsub = lane >> 5;            // head within pair
    const int p    = (lane >> 2) & 7;      // point (bits 2..4)
    const int d8   = lane & 3;             // 8-value quad (bits 0..1)

    const int orig = blockIdx.x;                      // 0..4999
    const int wg   = (orig & 7) * 625 + (orig >> 3);  // bijective (5000%8==0)
    const int b    = wg / 2500;
    const int bl0  = (wg - b * 2500) * 16;            // bn_local0, 0..39984
    const int i0   = bl0 / 200;
    const int j0   = bl0 - i0 * 200;
    const int bn0  = b * N + bl0;

    const ushort* vb = proj_v16 + (size_t)b * N * 128;
    const int m  = lane & 15;
    const int kg = lane >> 4;
    const int col = (wv & 7) * 16 + m;

    // ---- upfront: both units' geometry + ow records ----
    int pix_t[2], h_t[2];
    float fi_t[2], fj_t[2];
    uint2 ow[2];
    #pragma unroll
    for (int t = 0; t < 2; ++t) {
        const int unit = t * 16 + wv;       // 0..31
        const int pix  = unit >> 1;
        pix_t[t] = pix;
        h_t[t]   = (unit & 1) * 2 + hsub;
        const int jr   = j0 + pix;
        const bool wr  = jr >= 200;
        fi_t[t] = (float)(i0 + (wr ? 1 : 0));
        fj_t[t] = (float)(wr ? jr - 200 : jr);
        ow[t] = *(const uint2*)(proj_s16 + (size_t)(bn0 + pix) * SC + (h_t[t] * 8 + p) * 4);
    }

    // ---- upfront: GEMM waves preload B-fragments + Q residual ----
    short8 wfrag[KS];
    float qv[4];
    if (wv < 8) {
        #pragma unroll
        for (int ks = 0; ks < KS; ++ks)
            wfrag[ks] = ((const short8*)wtp2)[ks * NF_O * 64 + wv * 64 + lane];
        #pragma unroll
        for (int r = 0; r < 4; ++r)
            qv[r] = __builtin_nontemporal_load(Q + (size_t)(bn0 + kg * 4 + r) * 128 + col);
    }

    #pragma unroll
    for (int t = 0; t < 2; ++t) {
        const float2 off = h2f2(ow[t].x);
        const float  wp  = h1f((ushort)(ow[t].y & 0xffff));

        const float ixf = fi_t[t] + off.x;
        const float iyf = fj_t[t] + off.y;
        const float x0f = floorf(ixf), y0f = floorf(iyf);
        const float lx = ixf - x0f, ly = iyf - y0f;
        const int x0 = (int)x0f, y0 = (int)y0f;
        const int x1 = x0 + 1,  y1 = y0 + 1;
        const int xc0 = min(max(x0, 0), X - 1), xc1 = min(max(x1, 0), X - 1);
        const int yc0 = min(max(y0, 0), Z - 1), yc1 = min(max(y1, 0), Z - 1);

        const float wx0 = ((unsigned)x0 < (unsigned)X) ? (1.f - lx) : 0.f;
        const float wx1 = ((unsigned)x1 < (unsigned)X) ? lx : 0.f;
        const float wy0 = (((unsigned)y0 < (unsigned)Z) ? (1.f - ly) : 0.f) * wp;
        const float wy1 = (((unsigned)y1 < (unsigned)Z) ? ly : 0.f) * wp;

        const h16x2 w00p = pkrtz(wx0 * wy0, wx0 * wy0);
        const h16x2 w10p = pkrtz(wx1 * wy0, wx1 * wy0);
        const h16x2 w01p = pkrtz(wx0 * wy1, wx0 * wy1);
        const h16x2 w11p = pkrtz(wx1 * wy1, wx1 * wy1);

        const int rb0 = yc0 * X, rb1 = yc1 * X;
        const int hb  = h_t[t] * 32 + d8 * 8;   // f16-elem offset in 128-elem row

        const uint4 c00 = *(const uint4*)(vb + (size_t)(rb0 + xc0) * 128 + hb);
        const uint4 c10 = *(const uint4*)(vb + (size_t)(rb0 + xc1) * 128 + hb);
        const uint4 c01 = *(const uint4*)(vb + (size_t)(rb1 + xc0) * 128 + hb);
        const uint4 c11 = *(const uint4*)(vb + (size_t)(rb1 + xc1) * 128 + hb);

        h16x2 a0 = (h16x2)0, a1 = (h16x2)0, a2 = (h16x2)0, a3 = (h16x2)0;
        #define VSA_ACC(c, wpk) { \
            a0 = __builtin_elementwise_fma(__builtin_bit_cast(h16x2, (c).x), wpk, a0); \
            a1 = __builtin_elementwise_fma(__builtin_bit_cast(h16x2, (c).y), wpk, a1); \
            a2 = __builtin_elementwise_fma(__builtin_bit_cast(h16x2, (c).z), wpk, a2); \
            a3 = __builtin_elementwise_fma(__builtin_bit_cast(h16x2, (c).w), wpk, a3); }
        VSA_ACC(c00, w00p)
        VSA_ACC(c10, w10p)
        VSA_ACC(c01, w01p)
        VSA_ACC(c11, w11p)
        #undef VSA_ACC

        // reduce over the 8 points (p = lane bits 2..4), within 32 lanes
        a0 += swzh<4>(a0);  a1 += swzh<4>(a1);  a2 += swzh<4>(a2);  a3 += swzh<4>(a3);
        a0 += swzh<8>(a0);  a1 += swzh<8>(a1);  a2 += swzh<8>(a2);  a3 += swzh<8>(a3);
        a0 += swzh<16>(a0); a1 += swzh<16>(a1); a2 += swzh<16>(a2); a3 += swzh<16>(a3);

        if (p == 0) {   // lanes {0..3, 32..35}: one 16B LDS store per head
            uint4 o;
            o.x = __builtin_bit_cast(unsigned, a0);
            o.y = __builtin_bit_cast(unsigned, a1);
            o.z = __builtin_bit_cast(unsigned, a2);
            o.w = __builtin_bit_cast(unsigned, a3);
            *(uint4*)(&tmp_lds[pix_t[t]][h_t[t] * 32 + d8 * 8]) = o;
        }
    }

    __syncthreads();
    if (wv >= 8) return;

    // ---- output GEMM phase: wave wv owns fragment wv (B preloaded) ----
    f32x4 acc = (f32x4){0.f, 0.f, 0.f, 0.f};
    #pragma unroll
    for (int ks = 0; ks < KS; ++ks) {
        short8 af = *(const short8*)(&tmp_lds[m][ks * 32 + kg * 8]);
        acc = __builtin_amdgcn_mfma_f32_16x16x32_f16(af, wfrag[ks], acc, 0, 0, 0);
    }

    const float bb = bias2[col];
    #pragma unroll
    for (int r = 0; r < 4; ++r) {
        const size_t gi = (size_t)(bn0 + kg * 4 + r) * 128 + col;
        __builtin_nontemporal_store(acc[r] + bb + qv[r], out + gi);
    }
}

// ---------------------------------------------------------------------------
extern "C" void kernel_launch(void* const* d_in, const int* in_sizes, int n_in,
                              void* d_out, int out_size, void* d_ws, size_t ws_size,
                              hipStream_t stream) {
    const float* Q     = (const float*)d_in[0];
    const float* Wv    = (const float*)d_in[1];
    const float* bv    = (const float*)d_in[2];
    const float* Woff  = (const float*)d_in[3];
    const float* boff  = (const float*)d_in[4];
    const float* Wattn = (const float*)d_in[5];
    const float* battn = (const float*)d_in[6];
    const float* Wout1 = (const float*)d_in[7];
    const float* bout1 = (const float*)d_in[8];
    const float* Wout2 = (const float*)d_in[9];
    const float* bout2 = (const float*)d_in[10];
    float* out = (float*)d_out;

    // Workspace: biasp f32[224] | b12 f32[128] | proj_s16 u16[BN][128] |
    //            proj_v16 u16[BN][128] | wtp | wtp2
    float*  biasp  = (float*)d_ws;
    float*  bias2  = biasp + 224;
    ushort* proj_s16 = (ushort*)(bias2 + 128);
    ushort* proj_v16 = proj_s16 + (size_t)BN * SC;
    ushort* wtp    = proj_v16 + (size_t)BN * 128;
    ushort* wtp2   = wtp + (size_t)KS * NF_P * 64 * 8;

    constexpr int NP = KS * NF_P * 64;                    // 3584
    constexpr int setup_blocks = 65 + (NP + 224 + 255) / 256;  // 65 + 15 = 80
    vsa_k_setup<<<setup_blocks, 256, 0, stream>>>(
        Wv, bv, Woff, boff, Wattn, battn, Wout1, bout1, Wout2, bout2,
        wtp, wtp2, biasp, bias2);
    vsa_k_proj<<<BN / 128, 512, 0, stream>>>(Q, wtp, biasp, proj_v16, proj_s16);
    vsa_k_so<<<BN / 16, 1024, 0, stream>>>(proj_v16, proj_s16, wtp2, bias2, Q, out);
}

// Round 22
// 83.473 us; speedup vs baseline: 1.3851x; 1.0001x over previous
//
#include <hip/hip_runtime.h>
#include <hip/hip_bf16.h>
#include <cstddef>

namespace {
constexpr int B  = 2;
constexpr int Z  = 200;
constexpr int X  = 200;
constexpr int C  = 128;
constexpr int H  = 4;
constexpr int P  = 8;
constexpr int N  = Z * X;       // 40000
constexpr int BN = B * N;       // 80000
constexpr int SC = 128;         // proj_s cols (f16): [hp][{offx,offy,wp,pad}]
constexpr int NF_P = 14;        // 224/16 output fragments (proj GEMM)
constexpr int NF_O = 8;         // 128/16 output fragments (out GEMM)
constexpr int KS   = 4;         // 128/32 K-steps

typedef __attribute__((ext_vector_type(8))) short short8;
typedef __attribute__((ext_vector_type(4))) float f32x4;
typedef _Float16 h16x2 __attribute__((ext_vector_type(2)));

__device__ inline ushort f2bf(float x) {
    __hip_bfloat16 h = __float2bfloat16(x);
    return *reinterpret_cast<ushort*>(&h);
}
__device__ inline unsigned packbf(float a, float b) {
    return (unsigned)f2bf(a) | ((unsigned)f2bf(b) << 16);
}
__device__ inline ushort f2h(float x) {
    _Float16 h = (_Float16)x;
    return __builtin_bit_cast(ushort, h);
}
__device__ inline float h1f(ushort u) {
    return (float)__builtin_bit_cast(_Float16, u);
}
__device__ inline float2 h2f2(unsigned u) {
    h16x2 h = __builtin_bit_cast(h16x2, u);
    return make_float2((float)h[0], (float)h[1]);
}
__device__ inline unsigned packh(float a, float b) {
    return (unsigned)f2h(a) | ((unsigned)f2h(b) << 16);
}
// packed f32->f16x2 convert (v_cvt_pkrtz_f16_f32), bit-cast to our h16x2
__device__ inline h16x2 pkrtz(float a, float b) {
    return __builtin_bit_cast(h16x2, __builtin_amdgcn_cvt_pkrtz(a, b));
}
// single-instruction lane xor-shuffles (BitMode ds_swizzle), within 32-lane groups
template <int MASK>
__device__ inline float swzx(float x) {
    constexpr int pat = (MASK << 10) | 0x1F;
    return __int_as_float(__builtin_amdgcn_ds_swizzle(__float_as_int(x), pat));
}
template <int MASK>
__device__ inline h16x2 swzh(h16x2 x) {
    constexpr int pat = (MASK << 10) | 0x1F;
    int t = __builtin_amdgcn_ds_swizzle(__builtin_bit_cast(int, x), pat);
    return __builtin_bit_cast(h16x2, t);
}
}

// ---------------------------------------------------------------------------
// SETUP (merged w12 + prep, no intermediate w12 buffer, no serial dependency):
//   blocks 0..64   : thread (k = blk*2 + tid>>7, c = tid&127) computes
//                    W12[k][c] = Wout1[k]·Wout2[:,c] (row 128 = bias) and
//                    scatter-writes it DIRECTLY into the packed f16 wtp2
//                    fragment table (or bias2 for k==128).
//   blocks 65..79  : wtp (bf16 proj-GEMM fragments) + biasp[224].
// ---------------------------------------------------------------------------
__global__ __launch_bounds__(256) void vsa_k_setup(
    const float* __restrict__ Wv,    const float* __restrict__ bv,
    const float* __restrict__ Woff,  const float* __restrict__ boff,
    const float* __restrict__ Wattn, const float* __restrict__ battn,
    const float* __restrict__ Wout1, const float* __restrict__ bout1,
    const float* __restrict__ Wout2, const float* __restrict__ bout2,
    ushort* __restrict__ wtp, ushort* __restrict__ wtp2,
    float* __restrict__ biasp, float* __restrict__ bias2)
{
    constexpr int NP = KS * NF_P * 64;   // 3584

    if (blockIdx.x < 65) {
        const int c = threadIdx.x & 127;
        const int k = blockIdx.x * 2 + (threadIdx.x >> 7);
        if (k > 128) return;
        const float* arow = (k < 128) ? (Wout1 + (size_t)k * 128) : bout1;
        float acc = (k < 128) ? 0.f : bout2[c];
        #pragma unroll 4
        for (int j = 0; j < 128; ++j)
            acc = fmaf(arow[j], Wout2[(size_t)j * 128 + c], acc);
        if (k < 128) {
            // scatter into wtp2[t*8 + e]: t = ks*(8*64) + f*64 + l
            const int ks = k >> 5;
            const int l  = (((k >> 3) & 3) << 4) | (c & 15);
            const int f  = c >> 4;
            const int t  = (ks * NF_O + f) * 64 + l;
            wtp2[(size_t)t * 8 + (k & 7)] = f2h(acc);
        } else {
            bias2[c] = acc;
        }
        return;
    }

    const int u = (blockIdx.x - 65) * 256 + threadIdx.x;
    if (u < NP) {
        int ks  = u / (NF_P * 64);
        int rem = u - ks * (NF_P * 64);
        int f = rem >> 6, l = rem & 63;
        int n  = f * 16 + (l & 15);
        int kb = ks * 32 + (l >> 4) * 8;
        float v[8];
        #pragma unroll
        for (int e = 0; e < 8; ++e) {
            int k = kb + e;
            if (n < 128)      v[e] = Wv[k * 128 + n];
            else if (n < 192) v[e] = Woff[k * 64 + (n - 128)];
            else              v[e] = Wattn[k * 32 + (n - 192)];
        }
        unsigned* dst = (unsigned*)(wtp + (size_t)u * 8);
        #pragma unroll
        for (int i = 0; i < 4; ++i) dst[i] = packbf(v[2*i], v[2*i+1]);
    } else if (u < NP + 224) {
        int c = u - NP;
        float bb;
        if (c < 128)      bb = bv[c];
        else if (c < 192) bb = boff[c - 128];
        else              bb = battn[c - 192];
        biasp[c] = bb;
    }
}

// ---------------------------------------------------------------------------
// Fused projection GEMM + softmax epilogue, LDS-STAGED B (r19 structure):
// 8-wave blocks stage the 57KB wtp table into LDS once; B-fragments come
// from ds_read_b128 — no L1/L2 B-reload stream.
// ---------------------------------------------------------------------------
__global__ __launch_bounds__(512) void vsa_k_proj(
    const float* __restrict__ Q, const ushort* __restrict__ wtp,
    const float* __restrict__ biasp,
    ushort* __restrict__ proj_v16, ushort* __restrict__ proj_s16)
{
    __shared__ ushort lds_wt[KS * NF_P * 64 * 8];   // 57344 B

    const int tid  = threadIdx.x;
    const int lane = tid & 63;
    const int wv   = tid >> 6;              // 0..7
    const int row0 = blockIdx.x * 128 + wv * 16;
    const int m  = lane & 15;
    const int kg = lane >> 4;

    // stage wtp -> LDS (3584 x 16B, fully coalesced)
    {
        const uint4* src = (const uint4*)wtp;
        uint4* dst = (uint4*)lds_wt;
        #pragma unroll
        for (int it = 0; it < 7; ++it)
            dst[it * 512 + tid] = src[it * 512 + tid];
    }
    __syncthreads();

    const float* qp = Q + (size_t)(row0 + m) * 128 + kg * 8;

    f32x4 acc[NF_P];
    #pragma unroll
    for (int f = 0; f < NF_P; ++f) acc[f] = (f32x4){0.f, 0.f, 0.f, 0.f};

    #pragma unroll
    for (int ks = 0; ks < KS; ++ks) {
        float4 a0 = *(const float4*)(qp + ks * 32);
        float4 a1 = *(const float4*)(qp + ks * 32 + 4);
        short8 af;
        af[0] = (short)f2bf(a0.x); af[1] = (short)f2bf(a0.y);
        af[2] = (short)f2bf(a0.z); af[3] = (short)f2bf(a0.w);
        af[4] = (short)f2bf(a1.x); af[5] = (short)f2bf(a1.y);
        af[6] = (short)f2bf(a1.z); af[7] = (short)f2bf(a1.w);
        const short8* wrow = (const short8*)lds_wt + ks * NF_P * 64 + lane;
        #pragma unroll
        for (int f = 0; f < NF_P; ++f)
            acc[f] = __builtin_amdgcn_mfma_f32_16x16x32_bf16(af, wrow[f * 64], acc[f], 0, 0, 0);
    }

    // values -> f16
    #pragma unroll
    for (int f = 0; f < 8; ++f) {
        const int col = f * 16 + m;
        const float bb = biasp[col];
        #pragma unroll
        for (int r = 0; r < 4; ++r)
            proj_v16[(size_t)(row0 + kg * 4 + r) * 128 + col] = f2h(acc[f][r] + bb);
    }
    // offsets -> f16 at [hp*4 + comp]
    #pragma unroll
    for (int f = 8; f < 12; ++f) {
        const int col = f * 16 + m;
        const float bb = biasp[col];
        const int c  = col - 128;          // 0..63
        const int hp = c >> 1, comp = c & 1;
        #pragma unroll
        for (int r = 0; r < 4; ++r)
            proj_s16[(size_t)(row0 + kg * 4 + r) * SC + hp * 4 + comp] = f2h(acc[f][r] + bb);
    }
    // attn logits -> softmax -> f16 weights at [hp*4 + 2]
    #pragma unroll
    for (int f = 12; f < 14; ++f) {
        const float bb = biasp[f * 16 + m];
        const int hp = (f - 12) * 16 + m;  // 0..31
        #pragma unroll
        for (int r = 0; r < 4; ++r) {
            float v = acc[f][r] + bb;
            float mx = v;
            mx = fmaxf(mx, swzx<1>(mx));
            mx = fmaxf(mx, swzx<2>(mx));
            mx = fmaxf(mx, swzx<4>(mx));
            float ex = __expf(v - mx);
            float sm = ex;
            sm += swzx<1>(sm); sm += swzx<2>(sm); sm += swzx<4>(sm);
            const float wp = ex / sm;
            proj_s16[(size_t)(row0 + kg * 4 + r) * SC + hp * 4 + 2] = f2h(wp);
        }
    }
}

// ---------------------------------------------------------------------------
// FUSED sampling + output GEMM, 16 waves/block; each wave runs two sampling
// units. ow records for BOTH units and the GEMM waves' B-fragments + Q
// residual are loaded UPFRONT (latency hidden under sampling math).
// Barrier. GEMM: waves 0..7 own one output fragment; waves 8..15 exit.
// XCD swizzle: 5000 blocks = 8 x 625.
// ---------------------------------------------------------------------------
__global__ __launch_bounds__(1024) void vsa_k_so(
    const ushort* __restrict__ proj_v16, const ushort* __restrict__ proj_s16,
    const ushort* __restrict__ wtp2, const float* __restrict__ bias2,
    const float* __restrict__ Q, float* __restrict__ out)
{
    __shared__ ushort tmp_lds[16][136];   // 16 rows x 128 f16, pad 8 (16B)

    const int lane = threadIdx.x & 63;
    const int wv   = threadIdx.x >> 6;     // wave 0..15
    const int hsub = lane >> 5;            // head within pair
    const int p    = (lane >> 2) & 7;      // point (bits 2..4)
    const int d8   = lane & 3;             // 8-value quad (bits 0..1)

    const int orig = blockIdx.x;                      // 0..4999
    const int wg   = (orig & 7) * 625 + (orig >> 3);  // bijective (5000%8==0)
    const int b    = wg / 2500;
    const int bl0  = (wg - b * 2500) * 16;            // bn_local0, 0..39984
    const int i0   = bl0 / 200;
    const int j0   = bl0 - i0 * 200;
    const int bn0  = b * N + bl0;

    const ushort* vb = proj_v16 + (size_t)b * N * 128;
    const int m  = lane & 15;
    const int kg = lane >> 4;
    const int col = (wv & 7) * 16 + m;

    // ---- upfront: both units' geometry + ow records ----
    int pix_t[2], h_t[2];
    float fi_t[2], fj_t[2];
    uint2 ow[2];
    #pragma unroll
    for (int t = 0; t < 2; ++t) {
        const int unit = t * 16 + wv;       // 0..31
        const int pix  = unit >> 1;
        pix_t[t] = pix;
        h_t[t]   = (unit & 1) * 2 + hsub;
        const int jr   = j0 + pix;
        const bool wr  = jr >= 200;
        fi_t[t] = (float)(i0 + (wr ? 1 : 0));
        fj_t[t] = (float)(wr ? jr - 200 : jr);
        ow[t] = *(const uint2*)(proj_s16 + (size_t)(bn0 + pix) * SC + (h_t[t] * 8 + p) * 4);
    }

    // ---- upfront: GEMM waves preload B-fragments + Q residual ----
    short8 wfrag[KS];
    float qv[4];
    if (wv < 8) {
        #pragma unroll
        for (int ks = 0; ks < KS; ++ks)
            wfrag[ks] = ((const short8*)wtp2)[ks * NF_O * 64 + wv * 64 + lane];
        #pragma unroll
        for (int r = 0; r < 4; ++r)
            qv[r] = __builtin_nontemporal_load(Q + (size_t)(bn0 + kg * 4 + r) * 128 + col);
    }

    #pragma unroll
    for (int t = 0; t < 2; ++t) {
        const float2 off = h2f2(ow[t].x);
        const float  wp  = h1f((ushort)(ow[t].y & 0xffff));

        const float ixf = fi_t[t] + off.x;
        const float iyf = fj_t[t] + off.y;
        const float x0f = floorf(ixf), y0f = floorf(iyf);
        const float lx = ixf - x0f, ly = iyf - y0f;
        const int x0 = (int)x0f, y0 = (int)y0f;
        const int x1 = x0 + 1,  y1 = y0 + 1;
        const int xc0 = min(max(x0, 0), X - 1), xc1 = min(max(x1, 0), X - 1);
        const int yc0 = min(max(y0, 0), Z - 1), yc1 = min(max(y1, 0), Z - 1);

        const float wx0 = ((unsigned)x0 < (unsigned)X) ? (1.f - lx) : 0.f;
        const float wx1 = ((unsigned)x1 < (unsigned)X) ? lx : 0.f;
        const float wy0 = (((unsigned)y0 < (unsigned)Z) ? (1.f - ly) : 0.f) * wp;
        const float wy1 = (((unsigned)y1 < (unsigned)Z) ? ly : 0.f) * wp;

        const h16x2 w00p = pkrtz(wx0 * wy0, wx0 * wy0);
        const h16x2 w10p = pkrtz(wx1 * wy0, wx1 * wy0);
        const h16x2 w01p = pkrtz(wx0 * wy1, wx0 * wy1);
        const h16x2 w11p = pkrtz(wx1 * wy1, wx1 * wy1);

        const int rb0 = yc0 * X, rb1 = yc1 * X;
        const int hb  = h_t[t] * 32 + d8 * 8;   // f16-elem offset in 128-elem row

        const uint4 c00 = *(const uint4*)(vb + (size_t)(rb0 + xc0) * 128 + hb);
        const uint4 c10 = *(const uint4*)(vb + (size_t)(rb0 + xc1) * 128 + hb);
        const uint4 c01 = *(const uint4*)(vb + (size_t)(rb1 + xc0) * 128 + hb);
        const uint4 c11 = *(const uint4*)(vb + (size_t)(rb1 + xc1) * 128 + hb);

        h16x2 a0 = (h16x2)0, a1 = (h16x2)0, a2 = (h16x2)0, a3 = (h16x2)0;
        #define VSA_ACC(c, wpk) { \
            a0 = __builtin_elementwise_fma(__builtin_bit_cast(h16x2, (c).x), wpk, a0); \
            a1 = __builtin_elementwise_fma(__builtin_bit_cast(h16x2, (c).y), wpk, a1); \
            a2 = __builtin_elementwise_fma(__builtin_bit_cast(h16x2, (c).z), wpk, a2); \
            a3 = __builtin_elementwise_fma(__builtin_bit_cast(h16x2, (c).w), wpk, a3); }
        VSA_ACC(c00, w00p)
        VSA_ACC(c10, w10p)
        VSA_ACC(c01, w01p)
        VSA_ACC(c11, w11p)
        #undef VSA_ACC

        // reduce over the 8 points (p = lane bits 2..4), within 32 lanes
        a0 += swzh<4>(a0);  a1 += swzh<4>(a1);  a2 += swzh<4>(a2);  a3 += swzh<4>(a3);
        a0 += swzh<8>(a0);  a1 += swzh<8>(a1);  a2 += swzh<8>(a2);  a3 += swzh<8>(a3);
        a0 += swzh<16>(a0); a1 += swzh<16>(a1); a2 += swzh<16>(a2); a3 += swzh<16>(a3);

        if (p == 0) {   // lanes {0..3, 32..35}: one 16B LDS store per head
            uint4 o;
            o.x = __builtin_bit_cast(unsigned, a0);
            o.y = __builtin_bit_cast(unsigned, a1);
            o.z = __builtin_bit_cast(unsigned, a2);
            o.w = __builtin_bit_cast(unsigned, a3);
            *(uint4*)(&tmp_lds[pix_t[t]][h_t[t] * 32 + d8 * 8]) = o;
        }
    }

    __syncthreads();
    if (wv >= 8) return;

    // ---- output GEMM phase: wave wv owns fragment wv (B preloaded) ----
    f32x4 acc = (f32x4){0.f, 0.f, 0.f, 0.f};
    #pragma unroll
    for (int ks = 0; ks < KS; ++ks) {
        short8 af = *(const short8*)(&tmp_lds[m][ks * 32 + kg * 8]);
        acc = __builtin_amdgcn_mfma_f32_16x16x32_f16(af, wfrag[ks], acc, 0, 0, 0);
    }

    const float bb = bias2[col];
    #pragma unroll
    for (int r = 0; r < 4; ++r) {
        const size_t gi = (size_t)(bn0 + kg * 4 + r) * 128 + col;
        __builtin_nontemporal_store(acc[r] + bb + qv[r], out + gi);
    }
}

// ---------------------------------------------------------------------------
extern "C" void kernel_launch(void* const* d_in, const int* in_sizes, int n_in,
                              void* d_out, int out_size, void* d_ws, size_t ws_size,
                              hipStream_t stream) {
    const float* Q     = (const float*)d_in[0];
    const float* Wv    = (const float*)d_in[1];
    const float* bv    = (const float*)d_in[2];
    const float* Woff  = (const float*)d_in[3];
    const float* boff  = (const float*)d_in[4];
    const float* Wattn = (const float*)d_in[5];
    const float* battn = (const float*)d_in[6];
    const float* Wout1 = (const float*)d_in[7];
    const float* bout1 = (const float*)d_in[8];
    const float* Wout2 = (const float*)d_in[9];
    const float* bout2 = (const float*)d_in[10];
    float* out = (float*)d_out;

    // Workspace: biasp f32[224] | b12 f32[128] | proj_s16 u16[BN][128] |
    //            proj_v16 u16[BN][128] | wtp | wtp2
    float*  biasp  = (float*)d_ws;
    float*  bias2  = biasp + 224;
    ushort* proj_s16 = (ushort*)(bias2 + 128);
    ushort* proj_v16 = proj_s16 + (size_t)BN * SC;
    ushort* wtp    = proj_v16 + (size_t)BN * 128;
    ushort* wtp2   = wtp + (size_t)KS * NF_P * 64 * 8;

    constexpr int NP = KS * NF_P * 64;                    // 3584
    constexpr int setup_blocks = 65 + (NP + 224 + 255) / 256;  // 65 + 15 = 80
    vsa_k_setup<<<setup_blocks, 256, 0, stream>>>(
        Wv, bv, Woff, boff, Wattn, battn, Wout1, bout1, Wout2, bout2,
        wtp, wtp2, biasp, bias2);
    vsa_k_proj<<<BN / 128, 512, 0, stream>>>(Q, wtp, biasp, proj_v16, proj_s16);
    vsa_k_so<<<BN / 16, 1024, 0, stream>>>(proj_v16, proj_s16, wtp2, bias2, Q, out);
}